// Round 8
// baseline (532.899 us; speedup 1.0000x reference)
//
#include <hip/hip_runtime.h>
#include <cstdint>

#define M_DIM 8192
#define K_DIM 4096
#define N_DIM 12288
#define KT 32  // K-tiles of BK=128 int8 (128 B per row)

using i32x4 = __attribute__((ext_vector_type(4))) int;

__device__ inline void gload_lds16(const void* g, void* l) {
    __builtin_amdgcn_global_load_lds(
        (const __attribute__((address_space(1))) void*)g,
        (__attribute__((address_space(3))) void*)l,
        16, 0, 0);
}

// ---------------- fused: per-row quant (blocks 0..M-1) + weight repack ----------------
__global__ __launch_bounds__(256) void quant_pack(const float* __restrict__ x,
                                                  const int* __restrict__ w32,
                                                  int8_t* __restrict__ qa,
                                                  float* __restrict__ ascale,
                                                  int8_t* __restrict__ wq) {
    const int t = threadIdx.x;
    if (blockIdx.x < M_DIM) {
        const int row = blockIdx.x;
        const float4* xr = (const float4*)(x + (size_t)row * K_DIM);
        float4 v[4];
        float amax = 0.0f;
#pragma unroll
        for (int c = 0; c < 4; ++c) {
            v[c] = xr[t + 256 * c];
            amax = fmaxf(amax, fmaxf(fmaxf(fabsf(v[c].x), fabsf(v[c].y)),
                                     fmaxf(fabsf(v[c].z), fabsf(v[c].w))));
        }
#pragma unroll
        for (int off = 32; off > 0; off >>= 1)
            amax = fmaxf(amax, __shfl_xor(amax, off));
        __shared__ float smax[4];
        if ((t & 63) == 0) smax[t >> 6] = amax;
        __syncthreads();
        amax = fmaxf(fmaxf(smax[0], smax[1]), fmaxf(smax[2], smax[3]));
        const float sc = amax * (1.0f / 127.0f);
        const float inv = (amax > 0.0f) ? (127.0f / amax) : 0.0f;
        if (t == 0) ascale[row] = sc;

        int* q32 = (int*)(qa + (size_t)row * K_DIM);
#pragma unroll
        for (int c = 0; c < 4; ++c) {
            int q0 = (int)rintf(v[c].x * inv);
            int q1 = (int)rintf(v[c].y * inv);
            int q2 = (int)rintf(v[c].z * inv);
            int q3 = (int)rintf(v[c].w * inv);
            q0 = min(127, max(-128, q0));
            q1 = min(127, max(-128, q1));
            q2 = min(127, max(-128, q2));
            q3 = min(127, max(-128, q3));
            q32[t + 256 * c] = (q0 & 255) | ((q1 & 255) << 8) | ((q2 & 255) << 16) | (q3 << 24);
        }
    } else {
        const int pb = blockIdx.x - M_DIM;  // 0..2047
        const size_t total4 = (size_t)N_DIM * K_DIM / 4;
        const size_t stride = (size_t)2048 * 256;
        int* out32 = (int*)wq;
        for (size_t i = (size_t)pb * 256 + t; i < total4; i += stride) {
            const int4 v = ((const int4*)w32)[i];
            out32[i] = (v.x & 255) | ((v.y & 255) << 8) | ((v.z & 255) << 16) | (v.w << 24);
        }
    }
}

// ---- int8 GEMM: 256x256, BK=128, dbuf LDS, 4 phases/K-tile, m201-style placement ----
__global__ __launch_bounds__(512, 2) void gemm_i8(const int8_t* __restrict__ qa,
                                                  const int8_t* __restrict__ wq,
                                                  const float* __restrict__ ascale,
                                                  const float* __restrict__ wscale,
                                                  const float* __restrict__ bias,
                                                  float* __restrict__ out) {
    __shared__ int8_t lds[2][2][32768];  // [slot][A,B][256 rows x 128 B] = 128 KiB

    const int t = threadIdx.x;
    const int lane = t & 63;
    const int wave = t >> 6;       // 0..7
    const int wm = wave >> 2;      // 0..1 -> 128 rows of A
    const int wn = wave & 3;       // 0..3 -> 64 rows of B (cols of C)
    const int lrow = lane & 15;
    const int lk = lane >> 4;      // 0..3 (16B sub-slot within 64B k-slice)
    const int sw7 = lrow & 7;      // read-side XOR swizzle

    // XCD-aware bijective swizzle: 1536 = 8 * 192
    const int flat = blockIdx.x;
    const int sw = (flat & 7) * 192 + (flat >> 3);
    const int bm = sw / 48;  // 0..31
    const int bn = sw % 48;  // 0..47

    // staging: linear LDS dest (slot c*8192 + t*16); GLOBAL k-slot g = sl ^ (row&7)
    // — same involution the reader applies (verified: 0 bank conflicts).
    const int srow = t >> 3;                 // 0..63
    const int g = (t & 7) ^ (srow & 7);      // row&7 invariant under +64c

#define STAGE_OP(ptr, sb, op, rowbase, jt)                                     \
    {                                                                          \
        _Pragma("unroll") for (int c = 0; c < 4; ++c)                          \
            gload_lds16(ptr + (size_t)((rowbase) + srow + 64 * c) * K_DIM +    \
                            (size_t)g * 16 + (size_t)(jt) * 128,               \
                        &lds[sb][op][c * 8192 + t * 16]);                      \
    }

#define READ_A(dst, LA, mh)                                                    \
    {                                                                          \
        _Pragma("unroll") for (int mf = 0; mf < 4; ++mf)                       \
            _Pragma("unroll") for (int ks = 0; ks < 2; ++ks)                   \
                dst[mf][ks] = *(const i32x4*)&LA[(wm * 128 + (mh)*64 +         \
                                                 mf * 16 + lrow) * 128 +       \
                                                ((((ks << 2) | lk) ^ sw7) << 4)]; \
    }
#define READ_B(dst, LB, nh)                                                    \
    {                                                                          \
        _Pragma("unroll") for (int nf = 0; nf < 2; ++nf)                       \
            _Pragma("unroll") for (int ks = 0; ks < 2; ++ks)                   \
                dst[nf][ks] = *(const i32x4*)&LB[(wn * 64 + (nh)*32 +          \
                                                 nf * 16 + lrow) * 128 +       \
                                                ((((ks << 2) | lk) ^ sw7) << 4)]; \
    }
#define MM(AH, BH, mh, nh)                                                     \
    {                                                                          \
        __builtin_amdgcn_s_setprio(1);                                         \
        _Pragma("unroll") for (int ks = 0; ks < 2; ++ks)                       \
            _Pragma("unroll") for (int mf = 0; mf < 4; ++mf)                   \
                _Pragma("unroll") for (int nf = 0; nf < 2; ++nf)               \
                    acc[(mh)*4 + mf][(nh)*2 + nf] =                            \
                        __builtin_amdgcn_mfma_i32_16x16x64_i8(                 \
                            AH[mf][ks], BH[nf][ks],                            \
                            acc[(mh)*4 + mf][(nh)*2 + nf], 0, 0, 0);           \
        __builtin_amdgcn_s_setprio(0);                                         \
    }
#define LGKM0_PIN                                                              \
    asm volatile("s_waitcnt lgkmcnt(0)" ::: "memory");                         \
    __builtin_amdgcn_sched_barrier(0);
#define BARRIER __builtin_amdgcn_s_barrier();

    i32x4 acc[8][4] = {};
    i32x4 a0[4][2], a1[4][2], b0[2][2], b1[2][2];

    // prologue: stage tile 0, drain, barrier
    STAGE_OP(qa, 0, 0, bm * 256, 0);
    STAGE_OP(wq, 0, 1, bn * 256, 0);
    asm volatile("s_waitcnt vmcnt(0)" ::: "memory");
    BARRIER;

    for (int j = 0; j < KT; ++j) {
        const int cs = j & 1;
        const int ns = cs ^ 1;
        const int8_t* __restrict__ LA = lds[cs][0];
        const int8_t* __restrict__ LB = lds[cs][1];

        // ph0: reads issued BEFORE barrier (latency hides under barrier skew);
        //      stage A(j+1) alongside.
        READ_A(a0, LA, 0);
        READ_B(b0, LB, 0);
        if (j + 1 < KT) STAGE_OP(qa, ns, 0, bm * 256, j + 1);
        BARRIER;
        LGKM0_PIN;
        MM(a0, b0, 0, 0);
        BARRIER;

        // ph1: read b1 | stage B(j+1) | barrier | MM(a0,b1)
        READ_B(b1, LB, 1);
        if (j + 1 < KT) STAGE_OP(wq, ns, 1, bn * 256, j + 1);
        BARRIER;
        LGKM0_PIN;
        MM(a0, b1, 0, 1);
        BARRIER;

        // ph2: read a1 | barrier | MM(a1,b1)
        READ_A(a1, LA, 1);
        BARRIER;
        LGKM0_PIN;
        MM(a1, b1, 1, 1);
        BARRIER;

        // ph3: tile-(j+1) landing wait (loads 2-3 phases old -> cheap drain),
        //      then MM(a1,b0) purely from registers.
        asm volatile("s_waitcnt vmcnt(0)" ::: "memory");
        BARRIER;
        __builtin_amdgcn_sched_barrier(0);
        MM(a1, b0, 1, 0);
        BARRIER;
    }

    // epilogue: C/D layout col = lane&15, row = (lane>>4)*4 + j
    const int r0 = bm * 256 + wm * 128;
    const int c0 = bn * 256 + wn * 64;
    float asc[8][4];
#pragma unroll
    for (int m = 0; m < 8; ++m)
#pragma unroll
        for (int jj = 0; jj < 4; ++jj)
            asc[m][jj] = ascale[r0 + m * 16 + lk * 4 + jj];
#pragma unroll
    for (int n = 0; n < 4; ++n) {
        const int col = c0 + n * 16 + lrow;
        const float wsc = wscale[col];
        const float bb = bias[col];
#pragma unroll
        for (int m = 0; m < 8; ++m) {
#pragma unroll
            for (int jj = 0; jj < 4; ++jj) {
                const int row = r0 + m * 16 + lk * 4 + jj;
                out[(size_t)row * N_DIM + col] = (float)acc[m][n][jj] * asc[m][jj] * wsc + bb;
            }
        }
    }
}

extern "C" void kernel_launch(void* const* d_in, const int* in_sizes, int n_in,
                              void* d_out, int out_size, void* d_ws, size_t ws_size,
                              hipStream_t stream) {
    const float* x = (const float*)d_in[0];
    const int* w32 = (const int*)d_in[1];  // int8 weights arrive as int32
    const float* wscale = (const float*)d_in[2];
    const float* bias = (const float*)d_in[3];
    float* out = (float*)d_out;

    int8_t* qa = (int8_t*)d_ws;                                     // M*K int8
    float* ascale = (float*)((char*)d_ws + (size_t)M_DIM * K_DIM);  // M f32
    int8_t* wq = (int8_t*)((char*)d_ws + (size_t)M_DIM * K_DIM +
                           (size_t)M_DIM * sizeof(float));          // N*K int8

    quant_pack<<<M_DIM + 2048, 256, 0, stream>>>(x, w32, qa, ascale, wq);
    gemm_i8<<<1536, 512, 0, stream>>>(qa, wq, ascale, wscale, bias, out);
}